// Round 9
// baseline (309.537 us; speedup 1.0000x reference)
//
#include <hip/hip_runtime.h>
#include <stdint.h>

// ---------------------------------------------------------------------------
// SelfAttention: B=4, S=2048, E=1024 (single head) — R8 structure
//   q = Xq @ Wq^T ; k = Xk @ Wk^T ; vT = Wv @ Xv^T     (merged: 1 dispatch)
//   P = exp(q k^T / 32) ; out = (P @ v) / rowsum (epilogue atomics)
// R9 change: MFMA 16x16x32 -> 32x32x16 (m119: 2495 vs 2075 TF ceiling, +15%
// FLOP/cyc, half the MFMA issue slots; same ds_read count & acc regs).
// Layouts: C/D row=(reg&3)+8*(reg>>2)+4*(lane>>5), col=lane&31 (m74/m101).
//          A/B: row=lane&31, k=(lane>>5)*8+j  (extrapolated from 16x16).
// LDS swizzle (quarter-wave conflict rule): phys chunk = c ^ (row&7);
// read c = s*2+(lane>>5) -> 2 lanes/bank-quad per quarter = free.
// ---------------------------------------------------------------------------

typedef __attribute__((ext_vector_type(8))) short short8;        // 8 x bf16
typedef __attribute__((ext_vector_type(16))) float floatx16;     // 32x32 acc
typedef __attribute__((ext_vector_type(4))) unsigned short u16x4;
typedef __attribute__((ext_vector_type(4))) float f32x4v;

__device__ __forceinline__ unsigned short f32_to_bf16(float f) {
    union { float f; unsigned u; } c; c.f = f;
    unsigned u = c.u;
    return (unsigned short)((u + 0x7fffu + ((u >> 16) & 1u)) >> 16);  // RNE
}

// ---- merged fp32->bf16 converts (3x input, 3x weight) + rowsum zero ------
__global__ __launch_bounds__(256) void cvt_all(
    const float* __restrict__ q, const float* __restrict__ k,
    const float* __restrict__ v, const float* __restrict__ wq,
    const float* __restrict__ wk, const float* __restrict__ wv,
    unsigned short* __restrict__ Xq, unsigned short* __restrict__ Xk,
    unsigned short* __restrict__ Xv, unsigned short* __restrict__ Wq,
    unsigned short* __restrict__ Wk, unsigned short* __restrict__ Wv,
    float* __restrict__ rowsum) {
    const long NTE4 = 2097152;  // 8192*1024/4
    const long NW4  = 262144;   // 1024*1024/4
    long i = (long)blockIdx.x * 256 + threadIdx.x;
    const float* src;
    unsigned short* dst;
    long j;
    if (i < 3 * NTE4) {
        int a = (int)(i / NTE4); j = i - (long)a * NTE4;
        src = a == 0 ? q : a == 1 ? k : v;
        dst = a == 0 ? Xq : a == 1 ? Xk : Xv;
    } else {
        i -= 3 * NTE4;
        if (i < 3 * NW4) {
            int a = (int)(i / NW4); j = i - (long)a * NW4;
            src = a == 0 ? wq : a == 1 ? wk : wv;
            dst = a == 0 ? Wq : a == 1 ? Wk : Wv;
        } else {
            i -= 3 * NW4;           // rowsum[0..8191] = 0
            ((f32x4v*)rowsum)[i] = (f32x4v)0.0f;
            return;
        }
    }
    f32x4v f = ((const f32x4v*)src)[j];
    u16x4 o;
#pragma unroll
    for (int t = 0; t < 4; ++t) o[t] = f32_to_bf16(f[t]);
    ((u16x4*)dst)[j] = o;
}

// ---- NT GEMM body: C[m][n] = f(scale * sum_k A[m][k] * B[n][k]) ----------
// 128x128 tile, BK=64, 4 waves (2x2), per wave 64x64 = 2x2 of 32x32x16 MFMA,
// 4 k-steps per BK. G2L width-16 staging, xor chunk swizzle.
#define BM 128
#define BN 128
#define BK 64

#define G2L(g, l) __builtin_amdgcn_global_load_lds( \
    (__attribute__((address_space(1))) void*)(void*)(g), \
    (__attribute__((address_space(3))) void*)(l), 16, 0, 0)

// EPI: 0 = store bf16; 1 = store bf16 exp(x*scale) + rowsum atomics;
//      2 = store fp32 x / rowsum[row]
template <int EPI>
__device__ __forceinline__ void gemm_body(
    const unsigned short* __restrict__ A, const unsigned short* __restrict__ B,
    void* __restrict__ Cv, int lda, int ldb, int ldc, int K, float scale,
    float* __restrict__ rowsum, int m0, int n0) {
    __shared__ unsigned short As[BM * BK];
    __shared__ unsigned short Bs[BN * BK];

    const int tid  = threadIdx.x;
    const int wave = tid >> 6;
    const int lane = tid & 63;
    const int l31  = lane & 31;   // MFMA row/col within 32
    const int half = lane >> 5;   // k-block index
    const int wm   = wave >> 1;   // wave tile 2x2
    const int wn   = wave & 1;

    const int srow8 = lane >> 3;                 // row within 8-row group
    const int gcol  = ((lane & 7) ^ srow8) * 8;  // swizzled global col (shorts)

    floatx16 acc[2][2];
#pragma unroll
    for (int i = 0; i < 2; ++i)
#pragma unroll
        for (int j = 0; j < 2; ++j) acc[i][j] = (floatx16)0.0f;

    for (int k0 = 0; k0 < K; k0 += BK) {
#pragma unroll
        for (int i = 0; i < 4; ++i) {
            const int rbase = wave * 32 + i * 8;
            G2L(A + (size_t)(m0 + rbase + srow8) * lda + k0 + gcol,
                &As[rbase * BK]);
            G2L(B + (size_t)(n0 + rbase + srow8) * ldb + k0 + gcol,
                &Bs[rbase * BK]);
        }
        __syncthreads();

#pragma unroll
        for (int s = 0; s < 4; ++s) {
            // global chunk for k-range [s*16 + half*8, +8) is s*2+half
            const int phys = ((s * 2 + half) ^ (lane & 7)) * 8;
            short8 af[2], bf[2];
#pragma unroll
            for (int t = 0; t < 2; ++t) {
                af[t] = *(const short8*)&As[(wm * 64 + t * 32 + l31) * BK + phys];
                bf[t] = *(const short8*)&Bs[(wn * 64 + t * 32 + l31) * BK + phys];
            }
#pragma unroll
            for (int mt = 0; mt < 2; ++mt)
#pragma unroll
                for (int nt = 0; nt < 2; ++nt)
                    acc[mt][nt] = __builtin_amdgcn_mfma_f32_32x32x16_bf16(
                        af[mt], bf[nt], acc[mt][nt], 0, 0, 0);
        }
        __syncthreads();
    }

    // epilogue: D row = (reg&3) + 8*(reg>>2) + 4*half, col = l31 (m74/m101)
    if constexpr (EPI == 0) {
        unsigned short* C = (unsigned short*)Cv;
#pragma unroll
        for (int mt = 0; mt < 2; ++mt)
#pragma unroll
            for (int nt = 0; nt < 2; ++nt)
#pragma unroll
                for (int r = 0; r < 16; ++r) {
                    const int row = m0 + wm * 64 + mt * 32 +
                                    (r & 3) + 8 * (r >> 2) + 4 * half;
                    const int col = n0 + wn * 64 + nt * 32 + l31;
                    C[(size_t)row * ldc + col] = f32_to_bf16(acc[mt][nt][r]);
                }
    } else if constexpr (EPI == 1) {
        unsigned short* C = (unsigned short*)Cv;
        float psum[2][16];
#pragma unroll
        for (int mt = 0; mt < 2; ++mt)
#pragma unroll
            for (int r = 0; r < 16; ++r) psum[mt][r] = 0.0f;
#pragma unroll
        for (int mt = 0; mt < 2; ++mt)
#pragma unroll
            for (int nt = 0; nt < 2; ++nt)
#pragma unroll
                for (int r = 0; r < 16; ++r) {
                    const int row = m0 + wm * 64 + mt * 32 +
                                    (r & 3) + 8 * (r >> 2) + 4 * half;
                    const int col = n0 + wn * 64 + nt * 32 + l31;
                    const float p = __expf(acc[mt][nt][r] * scale);
                    psum[mt][r] += p;
                    C[(size_t)row * ldc + col] = f32_to_bf16(p);
                }
        // reduce over the 32 col-lanes (bits 0..4 of lane)
#pragma unroll
        for (int off = 1; off <= 16; off <<= 1)
#pragma unroll
            for (int mt = 0; mt < 2; ++mt)
#pragma unroll
                for (int r = 0; r < 16; ++r)
                    psum[mt][r] += __shfl_xor(psum[mt][r], off);
        if (l31 == 0) {
#pragma unroll
            for (int mt = 0; mt < 2; ++mt)
#pragma unroll
                for (int r = 0; r < 16; ++r)
                    atomicAdd(&rowsum[m0 + wm * 64 + mt * 32 +
                                      (r & 3) + 8 * (r >> 2) + 4 * half],
                              psum[mt][r]);
        }
    } else {
        float* C = (float*)Cv;
#pragma unroll
        for (int mt = 0; mt < 2; ++mt)
#pragma unroll
            for (int r = 0; r < 16; ++r) {
                const int row = m0 + wm * 64 + mt * 32 +
                                (r & 3) + 8 * (r >> 2) + 4 * half;
                const float inv = 1.0f / rowsum[row];
#pragma unroll
                for (int nt = 0; nt < 2; ++nt) {
                    const int col = n0 + wn * 64 + nt * 32 + l31;
                    C[(size_t)row * ldc + col] = acc[mt][nt][r] * inv;
                }
            }
    }
}

// ---- merged projections: z=0 q, z=1 k, z=2 vT (x/y grid roles swapped) ---
__global__ __launch_bounds__(256, 4) void proj_kernel(
    const unsigned short* __restrict__ Xq, const unsigned short* __restrict__ Wq,
    unsigned short* __restrict__ qb,
    const unsigned short* __restrict__ Xk, const unsigned short* __restrict__ Wk,
    unsigned short* __restrict__ kb,
    const unsigned short* __restrict__ Wv, const unsigned short* __restrict__ Xv,
    unsigned short* __restrict__ vT) {
    const int z = blockIdx.z;
    const unsigned short* A = z == 0 ? Xq : z == 1 ? Xk : Wv;
    const unsigned short* B = z == 0 ? Wq : z == 1 ? Wk : Xv;
    unsigned short* C = z == 0 ? qb : z == 1 ? kb : vT;
    int m0, n0, ldc;
    if (z < 2) { m0 = blockIdx.x * BM; n0 = blockIdx.y * BN; ldc = 1024; }
    else       { m0 = blockIdx.y * BM; n0 = blockIdx.x * BN; ldc = 8192; }
    gemm_body<0>(A, B, C, 1024, 1024, ldc, 1024, 1.0f, nullptr, m0, n0);
}

__global__ __launch_bounds__(256, 4) void scores_kernel(
    const unsigned short* __restrict__ qb, const unsigned short* __restrict__ kb,
    unsigned short* __restrict__ Sc, float* __restrict__ rowsum) {
    const long z = blockIdx.z;
    gemm_body<1>(qb + z * 2048 * 1024, kb + z * 2048 * 1024,
                 Sc + z * 2048 * 2048, 1024, 1024, 2048, 1024,
                 1.0f / 32.0f, rowsum + z * 2048,
                 blockIdx.x * BM, blockIdx.y * BN);
}

__global__ __launch_bounds__(256, 4) void pv_kernel(
    const unsigned short* __restrict__ Sc, const unsigned short* __restrict__ vT,
    float* __restrict__ out, float* __restrict__ rowsum) {
    const long z = blockIdx.z;
    gemm_body<2>(Sc + z * 2048 * 2048, vT + z * 2048,
                 out + z * 2048 * 1024, 2048, 8192, 1024, 2048,
                 1.0f, rowsum + z * 2048,
                 blockIdx.x * BM, blockIdx.y * BN);
}

// ---------------------------------------------------------------------------
extern "C" void kernel_launch(void* const* d_in, const int* in_sizes, int n_in,
                              void* d_out, int out_size, void* d_ws, size_t ws_size,
                              hipStream_t stream) {
    const float* q_in = (const float*)d_in[0];
    const float* k_in = (const float*)d_in[1];
    const float* v_in = (const float*)d_in[2];
    const float* Qw_f = (const float*)d_in[3];
    const float* Kw_f = (const float*)d_in[4];
    const float* Vw_f = (const float*)d_in[5];
    float* out = (float*)d_out;

    const int Bb = 4, S = 2048, E = 1024;
    const size_t TOK = (size_t)Bb * S;       // 8192
    const size_t NTE = TOK * E;              // 8,388,608
    const size_t NW  = (size_t)E * E;        // 1,048,576

    unsigned short* ws = (unsigned short*)d_ws;
    unsigned short* Xq = ws;            // [8192,1024]
    unsigned short* Xk = Xq + NTE;
    unsigned short* Xv = Xk + NTE;
    unsigned short* Wq = Xv + NTE;      // [1024,1024]
    unsigned short* Wk = Wq + NW;
    unsigned short* Wv = Wk + NW;
    unsigned short* qb = Wv + NW;       // [8192,1024]
    unsigned short* kb = qb + NTE;
    unsigned short* vT = kb + NTE;      // [1024 e][8192 tok]
    unsigned short* Sc = vT + NTE;      // [4][2048][2048] exp-scores
    float* rowsum = (float*)(Sc + (size_t)Bb * S * S);  // [4][2048]

    // 1) all converts + rowsum zero, one dispatch
    {
        const long G = 3 * (long)(NTE / 4) + 3 * (long)(NW / 4) + (Bb * S / 4);
        cvt_all<<<(unsigned)(G / 256), 256, 0, stream>>>(
            q_in, k_in, v_in, Qw_f, Kw_f, Vw_f,
            Xq, Xk, Xv, Wq, Wk, Wv, rowsum);
    }

    // 2) all three projections, one dispatch (1536 blocks)
    proj_kernel<<<dim3(TOK / BM, E / BN, 3), 256, 0, stream>>>(
        Xq, Wq, qb, Xk, Wk, kb, Wv, Xv, vT);

    // 3) P = exp(q k^T / 32) + fp32 rowsums
    scores_kernel<<<dim3(S / BM, S / BN, 4), 256, 0, stream>>>(
        qb, kb, Sc, rowsum);

    // 4) out = (P @ v) / rowsum
    pv_kernel<<<dim3(S / BM, E / BN, 4), 256, 0, stream>>>(
        Sc, vT, out, rowsum);
}